// Round 4
// baseline (904.717 us; speedup 1.0000x reference)
//
#include <hip/hip_runtime.h>

// DMPNN encoder, MI355X bf16-MFMA, round 4: position-space (dst-grouped) h layout.
//
// pos-space: position p corresponds to edge eidx[p] (edges grouped by dst).
//   fidx[p] = rev[eidx[p]]  (grouped by src => sidx[p]=src[fidx[p]] sorted)
//   pidx[p] = posOf[fidx[p]]  -- fix-point-free involution
//   hbuf[p] stores h(eidx[p])  => segsum is fully sequential.
// k_msg: msg(fidx[p]) = tmp[sidx[p]] - hbuf[p]  (both stream);
//   result h'(fidx[p]) stored at hbuf[pidx[p]].
//   Tiles = 64 involution pairs (plist[j], qlist[j]) -> read/write row-set closed
//   => single-buffer in-place safe.
// k_init: row p: [atomBf[sidx[p]] | bond[fidx[p]]] @ WiP -> hbuf[pidx[p]].
//
// MFMA 16x16x32 bf16 layouts (learn_hip m89/m91):
//   A frag: lane l holds A[m=l&15][k=(l>>4)*8+j]
//   B frag: lane l holds B[k=(l>>4)*8+j][n=l&15] == W[n][k] k-contiguous
//   D frag: reg r holds D[row=(l>>4)*4+r][col=l&15]
// Weight output channels permuted (c(p) below) so each lane's j=0/1 (j=2/3)
// fragments are adjacent channels -> epilogue stores packed u32 bf16x2.

typedef unsigned int u32;
typedef unsigned short u16;
using bf16x8 = __attribute__((ext_vector_type(8))) __bf16;
using f32x4  = __attribute__((ext_vector_type(4))) float;

#define NN 50000
#define NP 400000
#define NE 800000
#define AF 133
#define HID 128
#define ATU 68      // atomBf row stride in u32
#define KPU1 84     // k_init LDS stride; 80 data u32 = 160 cols = 5 chunks
#define KC1 5
#define KPU2 68     // k_msg stride; 64 data u32 = 128 cols = 4 chunks
#define KC2 4
#define KPU3 148    // k_out stride; 144 data u32 = 288 cols = 9 chunks
#define KC3 9
#define NCH 196     // scan chunks of 256 covering NN
#define PCH 3125    // chunks of 256 covering NE (pair compaction)

__device__ __forceinline__ u16 f2bf(float f) {
    union { float f; u32 u; } x; x.f = f;
    u32 r = x.u + 0x7fffu + ((x.u >> 16) & 1u);   // RNE
    return (u16)(r >> 16);
}
__device__ __forceinline__ float bf2f(u16 b) {
    union { u32 u; float f; } x; x.u = ((u32)b) << 16;
    return x.f;
}
__device__ __forceinline__ float lo16(u32 v) { return bf2f((u16)v); }
__device__ __forceinline__ float hi16(u32 v) { return bf2f((u16)(v >> 16)); }
__device__ __forceinline__ u32 pack2(float a, float b) {
    return (u32)f2bf(a) | ((u32)f2bf(b) << 16);
}
__device__ __forceinline__ u32 sub2(u32 t, u32 h) {
    return pack2(lo16(t) - lo16(h), hi16(t) - hi16(h));
}
__device__ __forceinline__ float relu(float v) { return v > 0.f ? v : 0.f; }

// ---------------- precompute kernels ----------------

__global__ void cvt_atom(const float* __restrict__ atom, u32* __restrict__ out) {
    int total = NN * ATU;
    for (int i = blockIdx.x * blockDim.x + threadIdx.x; i < total; i += gridDim.x * blockDim.x) {
        int n = i / ATU;
        int cu = i - n * ATU;
        int k = 2 * cu;
        float f0 = (k < AF) ? atom[n * AF + k] : 0.f;
        float f1 = (k + 1 < AF) ? atom[n * AF + k + 1] : 0.f;
        out[i] = pack2(f0, f1);
    }
}

__device__ __forceinline__ float wcol(const float* W, int n, int Kw, int len1, int off2, int len2, int k) {
    if (k < len1) return W[n * Kw + k];
    int j = k - off2;
    if (j >= 0 && j < len2) return W[n * Kw + len1 + j];
    return 0.f;
}
// Wp row p <- actual channel c(p) (output-channel permutation for packed stores)
__global__ void cvt_w(const float* __restrict__ W, u32* __restrict__ out,
                      int Kw, int KpU, int len1, int off2, int len2) {
    int total = 128 * KpU;
    for (int i = blockIdx.x * blockDim.x + threadIdx.x; i < total; i += gridDim.x * blockDim.x) {
        int p = i / KpU;
        int cu = i - p * KpU;
        int t = p & 63;
        int c = (p & 64) + 2 * (t & 15) + ((t >> 4) & 1) + 32 * ((t >> 5) & 1);
        int k = 2 * cu;
        out[i] = pack2(wcol(W, c, Kw, len1, off2, len2, k),
                       wcol(W, c, Kw, len1, off2, len2, k + 1));
    }
}

// ---------------- CSR build ----------------

__global__ void hist(const int* __restrict__ dst, int* __restrict__ cnt) {
    for (int e = blockIdx.x * blockDim.x + threadIdx.x; e < NE; e += gridDim.x * blockDim.x)
        atomicAdd(&cnt[dst[e]], 1);
}

__global__ void scan1(const int* __restrict__ cnt, int* __restrict__ lexc, int* __restrict__ chunkSum) {
    __shared__ int s[256];
    int t = threadIdx.x, idx = blockIdx.x * 256 + t;
    int v = (idx < NN) ? cnt[idx] : 0;
    s[t] = v; __syncthreads();
    for (int off = 1; off < 256; off <<= 1) {
        int x = (t >= off) ? s[t - off] : 0;
        __syncthreads();
        s[t] += x;
        __syncthreads();
    }
    if (idx < NN) lexc[idx] = s[t] - v;
    if (t == 255) chunkSum[blockIdx.x] = s[255];
}

__global__ void scan2(const int* __restrict__ chunkSum, int* __restrict__ chunkOff) {
    __shared__ int s[256];
    int t = threadIdx.x;
    int v = (t < NCH) ? chunkSum[t] : 0;
    s[t] = v; __syncthreads();
    for (int off = 1; off < 256; off <<= 1) {
        int x = (t >= off) ? s[t - off] : 0;
        __syncthreads();
        s[t] += x;
        __syncthreads();
    }
    if (t < NCH) chunkOff[t] = s[t] - v;
}

__global__ void scan3(const int* __restrict__ lexc, const int* __restrict__ chunkOff,
                      int* __restrict__ rowptr, int* __restrict__ cursor) {
    int idx = blockIdx.x * 256 + threadIdx.x;
    if (idx < NN) {
        int v = lexc[idx] + chunkOff[blockIdx.x];
        rowptr[idx] = v;
        cursor[idx] = v;
    }
    if (idx == 0) rowptr[NN] = NE;
}

__global__ void scatter(const int* __restrict__ dst, const int* __restrict__ rev,
                        int* __restrict__ cursor, int* __restrict__ fidx,
                        int* __restrict__ sidx, int* __restrict__ posOf) {
    for (int e = blockIdx.x * blockDim.x + threadIdx.x; e < NE; e += gridDim.x * blockDim.x) {
        int d = dst[e];
        int pos = atomicAdd(&cursor[d], 1);
        fidx[pos] = rev[e];
        sidx[pos] = d;        // = src[fidx[pos]], nondecreasing over pos
        posOf[e] = pos;
    }
}

// pidx[p] = posOf[fidx[p]]; per-chunk count of (p < pidx[p])
__global__ void pidx_build(const int* __restrict__ fidx, const int* __restrict__ posOf,
                           int* __restrict__ pidx, int* __restrict__ pcnt) {
    __shared__ int s[256];
    int t = threadIdx.x, p = blockIdx.x * 256 + t;
    int flag = 0;
    if (p < NE) {
        int q = posOf[fidx[p]];
        pidx[p] = q;
        flag = (p < q) ? 1 : 0;
    }
    s[t] = flag; __syncthreads();
    for (int off = 128; off >= 1; off >>= 1) {
        if (t < off) s[t] += s[t + off];
        __syncthreads();
    }
    if (t == 0) pcnt[blockIdx.x] = s[0];
}

__global__ void pscan(const int* __restrict__ pcnt, int* __restrict__ poff) {
    __shared__ int s[256];
    __shared__ int carry;
    int t = threadIdx.x;
    if (t == 0) carry = 0;
    __syncthreads();
    for (int base = 0; base < PCH; base += 256) {
        int i = base + t;
        int v = (i < PCH) ? pcnt[i] : 0;
        s[t] = v; __syncthreads();
        for (int off = 1; off < 256; off <<= 1) {
            int x = (t >= off) ? s[t - off] : 0;
            __syncthreads();
            s[t] += x;
            __syncthreads();
        }
        if (i < PCH) poff[i] = carry + s[t] - v;
        __syncthreads();
        if (t == 255) carry += s[255];
        __syncthreads();
    }
}

__global__ void compact(const int* __restrict__ pidx, const int* __restrict__ sidx,
                        const int* __restrict__ poff, int* __restrict__ plist,
                        int* __restrict__ qlist, int* __restrict__ sP, int* __restrict__ sQ) {
    __shared__ int s[256];
    int t = threadIdx.x, p = blockIdx.x * 256 + t;
    int q = 0, flag = 0;
    if (p < NE) {
        q = pidx[p];
        flag = (p < q) ? 1 : 0;
    }
    s[t] = flag; __syncthreads();
    for (int off = 1; off < 256; off <<= 1) {
        int x = (t >= off) ? s[t - off] : 0;
        __syncthreads();
        s[t] += x;
        __syncthreads();
    }
    if (flag) {
        int j = poff[blockIdx.x] + s[t] - 1;
        plist[j] = p;
        qlist[j] = q;
        sP[j] = sidx[p];
        sQ[j] = sidx[q];
    }
}

// ---------------- segment sum (pos-space: fully sequential rows) ----------------
__global__ __launch_bounds__(256)
void segsum(const int* __restrict__ rowptr, const u32* __restrict__ h, u32* __restrict__ tmp) {
    const int lane = threadIdx.x & 63;
    const int wv = threadIdx.x >> 6;
    const int rsel = lane >> 4;
    const int cg = lane & 15;
    const int nwaves = gridDim.x * 4;
    for (int n = blockIdx.x * 4 + wv; n < NN; n += nwaves) {
        int beg = rowptr[n], end = rowptr[n + 1];
        float a0 = 0, a1 = 0, a2 = 0, a3 = 0, a4 = 0, a5 = 0, a6 = 0, a7 = 0;
        int i = beg;
        for (; i + 8 <= end; i += 8) {
            uint4 hA = *(const uint4*)(h + (size_t)(i + rsel) * 64 + 4 * cg);
            uint4 hB = *(const uint4*)(h + (size_t)(i + 4 + rsel) * 64 + 4 * cg);
            a0 += lo16(hA.x) + lo16(hB.x); a1 += hi16(hA.x) + hi16(hB.x);
            a2 += lo16(hA.y) + lo16(hB.y); a3 += hi16(hA.y) + hi16(hB.y);
            a4 += lo16(hA.z) + lo16(hB.z); a5 += hi16(hA.z) + hi16(hB.z);
            a6 += lo16(hA.w) + lo16(hB.w); a7 += hi16(hA.w) + hi16(hB.w);
        }
        for (; i < end; i += 4) {
            if (i + rsel < end) {
                uint4 hA = *(const uint4*)(h + (size_t)(i + rsel) * 64 + 4 * cg);
                a0 += lo16(hA.x); a1 += hi16(hA.x);
                a2 += lo16(hA.y); a3 += hi16(hA.y);
                a4 += lo16(hA.z); a5 += hi16(hA.z);
                a6 += lo16(hA.w); a7 += hi16(hA.w);
            }
        }
        a0 += __shfl_xor(a0, 16); a0 += __shfl_xor(a0, 32);
        a1 += __shfl_xor(a1, 16); a1 += __shfl_xor(a1, 32);
        a2 += __shfl_xor(a2, 16); a2 += __shfl_xor(a2, 32);
        a3 += __shfl_xor(a3, 16); a3 += __shfl_xor(a3, 32);
        a4 += __shfl_xor(a4, 16); a4 += __shfl_xor(a4, 32);
        a5 += __shfl_xor(a5, 16); a5 += __shfl_xor(a5, 32);
        a6 += __shfl_xor(a6, 16); a6 += __shfl_xor(a6, 32);
        a7 += __shfl_xor(a7, 16); a7 += __shfl_xor(a7, 32);
        if (rsel == 0) {
            uint4 o;
            o.x = pack2(a0, a1); o.y = pack2(a2, a3);
            o.z = pack2(a4, a5); o.w = pack2(a6, a7);
            *(uint4*)(tmp + (size_t)n * 64 + 4 * cg) = o;
        }
    }
}

// ---------------- k_init: pos-sequential 128-row tiles, 4 waves (64x64) ----------------
__global__ __launch_bounds__(256, 3)
void k_init(const u32* __restrict__ atomBf, const float* __restrict__ bond,
            const int* __restrict__ fidx, const int* __restrict__ sidx,
            const int* __restrict__ pidx, const u32* __restrict__ Wp,
            u32* __restrict__ hout)
{
    __shared__ u32 As[128 * KPU1];   // 43008 B -> 3 blocks/CU
    const int tid = threadIdx.x;
    const int lane = tid & 63;
    const int wv = tid >> 6;
    const int ln = lane & 15;
    const int q  = lane >> 4;
    const int rowBase = 64 * (wv >> 1);
    const int cbU = 32 * (wv & 1);
    const int ntiles = NE / 128;

    const int srow = tid >> 1;
    const int half = tid & 1;

    for (int tile = blockIdx.x; tile < ntiles; tile += gridDim.x) {
        const int e0 = tile * 128;
        {
            int p = e0 + srow;
            const u32* ap = atomBf + (size_t)sidx[p] * ATU;
            u32* dr = As + srow * KPU1;
            if (half == 0) {
                #pragma unroll
                for (int j = 0; j < 10; ++j)
                    *(uint4*)(dr + 4 * j) = *(const uint4*)(ap + 4 * j);
            } else {
                #pragma unroll
                for (int j = 10; j < 17; ++j)
                    *(uint4*)(dr + 4 * j) = *(const uint4*)(ap + 4 * j);
                const float* bp = bond + (size_t)fidx[p] * 14;
                float2 b0 = *(const float2*)(bp + 0);
                float2 b1 = *(const float2*)(bp + 2);
                float2 b2 = *(const float2*)(bp + 4);
                float2 b3 = *(const float2*)(bp + 6);
                float2 b4 = *(const float2*)(bp + 8);
                float2 b5 = *(const float2*)(bp + 10);
                float2 b6 = *(const float2*)(bp + 12);
                *(uint4*)(dr + 68) = make_uint4(pack2(b0.x, b0.y), pack2(b1.x, b1.y),
                                                pack2(b2.x, b2.y), pack2(b3.x, b3.y));
                *(uint4*)(dr + 72) = make_uint4(pack2(b4.x, b4.y), pack2(b5.x, b5.y),
                                                pack2(b6.x, b6.y), 0u);
                *(uint4*)(dr + 76) = make_uint4(0u, 0u, 0u, 0u);
            }
        }
        __syncthreads();

        f32x4 acc[4][4] = {};
        #pragma unroll
        for (int kc = 0; kc < KC1; ++kc) {
            const int kHalf = kc * 16 + q * 4;
            bf16x8 a[4], b[4];
            #pragma unroll
            for (int i = 0; i < 4; ++i)
                a[i] = *(const bf16x8*)(&As[(rowBase + 16 * i + ln) * KPU1 + kHalf]);
            #pragma unroll
            for (int j = 0; j < 4; ++j)
                b[j] = *(const bf16x8*)(Wp + (64 * (wv & 1) + 16 * j + ln) * KPU1 + kHalf);
            #pragma unroll
            for (int i = 0; i < 4; ++i)
                #pragma unroll
                for (int j = 0; j < 4; ++j)
                    acc[i][j] = __builtin_amdgcn_mfma_f32_16x16x32_bf16(a[i], b[j], acc[i][j], 0, 0, 0);
        }
        __syncthreads();

        #pragma unroll
        for (int i = 0; i < 4; ++i) {
            #pragma unroll
            for (int r = 0; r < 4; ++r) {
                int wpos = pidx[e0 + rowBase + 16 * i + q * 4 + r];
                u32* orow = hout + (size_t)wpos * 64;
                orow[cbU + ln]      = pack2(relu(acc[i][0][r]), relu(acc[i][1][r]));
                orow[cbU + 16 + ln] = pack2(relu(acc[i][2][r]), relu(acc[i][3][r]));
            }
        }
    }
}

// ---------------- k_msg: 64 involution-pair tiles (rows 0..63 = plist, 64..127 = qlist) ----------------
__global__ __launch_bounds__(256, 4)
void k_msg(const int* __restrict__ plist, const int* __restrict__ qlist,
           const int* __restrict__ sP, const int* __restrict__ sQ,
           const u32* __restrict__ Wp, const u32* __restrict__ tmp,
           u32* __restrict__ h)
{
    __shared__ u32 As[128 * KPU2];   // 34816 B -> 4 blocks/CU
    const int tid = threadIdx.x;
    const int lane = tid & 63;
    const int wv = tid >> 6;
    const int ln = lane & 15;
    const int q  = lane >> 4;
    const int rowBase = 64 * (wv >> 1);
    const int cbU = 32 * (wv & 1);
    const int ntiles = NP / 64;

    const int srow = tid >> 1;
    const int half = tid & 1;

    for (int tile = blockIdx.x; tile < ntiles; tile += gridDim.x) {
        const int j0 = tile * 64;
        {
            int j = j0 + (srow & 63);
            int pos = (srow < 64) ? plist[j] : qlist[j];
            int sv  = (srow < 64) ? sP[j] : sQ[j];
            const u32* tp = tmp + (size_t)sv * 64 + half * 32;
            const u32* hp = h + (size_t)pos * 64 + half * 32;
            u32* dr = As + srow * KPU2 + half * 32;
            #pragma unroll
            for (int k = 0; k < 8; ++k) {
                uint4 tv = ((const uint4*)tp)[k];
                uint4 hv = ((const uint4*)hp)[k];
                uint4 o;
                o.x = sub2(tv.x, hv.x); o.y = sub2(tv.y, hv.y);
                o.z = sub2(tv.z, hv.z); o.w = sub2(tv.w, hv.w);
                ((uint4*)dr)[k] = o;
            }
        }
        __syncthreads();

        f32x4 acc[4][4] = {};
        #pragma unroll
        for (int kc = 0; kc < KC2; ++kc) {
            const int kHalf = kc * 16 + q * 4;
            bf16x8 a[4], b[4];
            #pragma unroll
            for (int i = 0; i < 4; ++i)
                a[i] = *(const bf16x8*)(&As[(rowBase + 16 * i + ln) * KPU2 + kHalf]);
            #pragma unroll
            for (int j = 0; j < 4; ++j)
                b[j] = *(const bf16x8*)(Wp + (64 * (wv & 1) + 16 * j + ln) * KPU2 + kHalf);
            #pragma unroll
            for (int i = 0; i < 4; ++i)
                #pragma unroll
                for (int j = 0; j < 4; ++j)
                    acc[i][j] = __builtin_amdgcn_mfma_f32_16x16x32_bf16(a[i], b[j], acc[i][j], 0, 0, 0);
        }
        __syncthreads();

        // row r<64 computes msg of edge fidx[plist[j]] -> store at qlist[j]; r>=64 -> plist[j]
        #pragma unroll
        for (int i = 0; i < 4; ++i) {
            #pragma unroll
            for (int r = 0; r < 4; ++r) {
                int rloc = rowBase + 16 * i + q * 4 + r;
                int j = j0 + (rloc & 63);
                int wpos = (rloc < 64) ? qlist[j] : plist[j];
                u32* orow = h + (size_t)wpos * 64;
                orow[cbU + ln]      = pack2(relu(acc[i][0][r]), relu(acc[i][1][r]));
                orow[cbU + 16 + ln] = pack2(relu(acc[i][2][r]), relu(acc[i][3][r]));
            }
        }
    }
}

// ---------------- k_out: 64-node tiles, 4 waves (32x64 each) ----------------
__global__ __launch_bounds__(256, 4)
void k_out(const u32* __restrict__ atomBf, const u32* __restrict__ Wp,
           const u32* __restrict__ tmp, float* __restrict__ out)
{
    __shared__ u32 As[64 * KPU3];   // 37888 B -> 4 blocks/CU
    const int tid = threadIdx.x;
    const int lane = tid & 63;
    const int wv = tid >> 6;
    const int ln = lane & 15;
    const int q  = lane >> 4;
    const int rowBase = 32 * (wv >> 1);
    const int colBase = 64 * (wv & 1);
    const int ntiles = (NN + 63) / 64;

    const int srow = tid >> 2;
    const int qt = tid & 3;
    const uint4 z4 = make_uint4(0u, 0u, 0u, 0u);

    for (int tile = blockIdx.x; tile < ntiles; tile += gridDim.x) {
        const int n0 = tile * 64;
        {
            int n = n0 + srow;
            bool ok = n < NN;
            const u32* ap = atomBf + (size_t)n * ATU;
            const u32* tp = tmp + (size_t)n * 64;
            u32* dr = As + srow * KPU3;
            if (qt == 0) {
                #pragma unroll
                for (int j = 0; j < 9; ++j)
                    *(uint4*)(dr + 4 * j) = ok ? *(const uint4*)(ap + 4 * j) : z4;
            } else if (qt == 1) {
                #pragma unroll
                for (int j = 9; j < 17; ++j)
                    *(uint4*)(dr + 4 * j) = ok ? *(const uint4*)(ap + 4 * j) : z4;
            } else if (qt == 2) {
                #pragma unroll
                for (int j = 0; j < 8; ++j)
                    *(uint4*)(dr + 68 + 4 * j) = ok ? *(const uint4*)(tp + 4 * j) : z4;
                *(uint4*)(dr + 132) = z4;
            } else {
                #pragma unroll
                for (int j = 8; j < 16; ++j)
                    *(uint4*)(dr + 68 + 4 * j) = ok ? *(const uint4*)(tp + 4 * j) : z4;
                *(uint4*)(dr + 136) = z4;
                *(uint4*)(dr + 140) = z4;
            }
        }
        __syncthreads();

        f32x4 acc[2][4] = {};
        #pragma unroll
        for (int kc = 0; kc < KC3; ++kc) {
            const int kHalf = kc * 16 + q * 4;
            bf16x8 a[2], b[4];
            #pragma unroll
            for (int i = 0; i < 2; ++i)
                a[i] = *(const bf16x8*)(&As[(rowBase + 16 * i + ln) * KPU3 + kHalf]);
            #pragma unroll
            for (int j = 0; j < 4; ++j)
                b[j] = *(const bf16x8*)(Wp + (colBase + 16 * j + ln) * KPU3 + kHalf);
            #pragma unroll
            for (int i = 0; i < 2; ++i)
                #pragma unroll
                for (int j = 0; j < 4; ++j)
                    acc[i][j] = __builtin_amdgcn_mfma_f32_16x16x32_bf16(a[i], b[j], acc[i][j], 0, 0, 0);
        }
        __syncthreads();

        #pragma unroll
        for (int i = 0; i < 2; ++i) {
            #pragma unroll
            for (int r = 0; r < 4; ++r) {
                int n = n0 + rowBase + 16 * i + q * 4 + r;
                if (n < NN) {
                    float2* orow = (float2*)(out + (size_t)n * HID);
                    float2 v01, v23;
                    v01.x = relu(acc[i][0][r]); v01.y = relu(acc[i][1][r]);
                    v23.x = relu(acc[i][2][r]); v23.y = relu(acc[i][3][r]);
                    orow[(colBase >> 1) + ln]      = v01;
                    orow[(colBase >> 1) + 16 + ln] = v23;
                }
            }
        }
    }
}

// ---------------- launch ----------------

extern "C" void kernel_launch(void* const* d_in, const int* in_sizes, int n_in,
                              void* d_out, int out_size, void* d_ws, size_t ws_size,
                              hipStream_t stream) {
    const float* atom = (const float*)d_in[0];   // [50000][133]
    const float* bond = (const float*)d_in[1];   // [800000][14]
    const float* Wi   = (const float*)d_in[2];   // [128][147]
    const float* Wh   = (const float*)d_in[3];   // [128][128]
    const float* Wo   = (const float*)d_in[4];   // [128][261]
    const int*   src  = (const int*)d_in[5]; (void)src;
    const int*   dst  = (const int*)d_in[6];
    const int*   rev  = (const int*)d_in[7];
    float* out = (float*)d_out;

    char* ws = (char*)d_ws;
    size_t off = 0;
    auto take = [&](size_t bytes) { char* p = ws + off; off = (off + bytes + 255) & ~(size_t)255; return p; };
    u32* hbuf   = (u32*)take((size_t)NE * 64 * 4);     // 204.8 MB  bf16 h (pos-layout)
    u32* tmp    = (u32*)take((size_t)NN * 64 * 4);     // 12.8 MB
    u32* atomBf = (u32*)take((size_t)NN * ATU * 4);    // 13.6 MB
    int* fidx   = (int*)take((size_t)NE * 4);
    int* sidx   = (int*)take((size_t)NE * 4);
    int* posOf  = (int*)take((size_t)NE * 4);
    int* pidx   = (int*)take((size_t)NE * 4);
    int* plist  = (int*)take((size_t)NP * 4);
    int* qlist  = (int*)take((size_t)NP * 4);
    int* sP     = (int*)take((size_t)NP * 4);
    int* sQ     = (int*)take((size_t)NP * 4);
    int* cnt    = (int*)take((size_t)NN * 4);
    int* lexc   = (int*)take((size_t)NN * 4);
    int* rowptr = (int*)take((size_t)(NN + 1) * 4);
    int* cursor = (int*)take((size_t)NN * 4);
    int* chunkSum = (int*)take(256 * 4);
    int* chunkOff = (int*)take(256 * 4);
    int* pcnt   = (int*)take((size_t)PCH * 4);
    int* poff   = (int*)take((size_t)PCH * 4);
    u32* WiP = (u32*)take(128 * KPU1 * 4);
    u32* WhP = (u32*)take(128 * KPU2 * 4);
    u32* WoP = (u32*)take(128 * KPU3 * 4);
    // total ~253 MB

    cvt_atom<<<2048, 256, 0, stream>>>(atom, atomBf);
    cvt_w<<<48, 256, 0, stream>>>(Wi, WiP, 147, KPU1, 133, 136, 14);
    cvt_w<<<48, 256, 0, stream>>>(Wh, WhP, 128, KPU2, 128, 1 << 20, 0);
    cvt_w<<<80, 256, 0, stream>>>(Wo, WoP, 261, KPU3, 133, 136, 128);

    hipMemsetAsync(cnt, 0, (size_t)NN * 4, stream);
    hist<<<1024, 256, 0, stream>>>(dst, cnt);
    scan1<<<NCH, 256, 0, stream>>>(cnt, lexc, chunkSum);
    scan2<<<1, 256, 0, stream>>>(chunkSum, chunkOff);
    scan3<<<NCH, 256, 0, stream>>>(lexc, chunkOff, rowptr, cursor);
    scatter<<<1024, 256, 0, stream>>>(dst, rev, cursor, fidx, sidx, posOf);
    pidx_build<<<PCH, 256, 0, stream>>>(fidx, posOf, pidx, pcnt);
    pscan<<<1, 256, 0, stream>>>(pcnt, poff);
    compact<<<PCH, 256, 0, stream>>>(pidx, sidx, poff, plist, qlist, sP, sQ);

    k_init<<<768, 256, 0, stream>>>(atomBf, bond, fidx, sidx, pidx, WiP, hbuf);
    segsum<<<2048, 256, 0, stream>>>(rowptr, hbuf, tmp);
    k_msg<<<1024, 256, 0, stream>>>(plist, qlist, sP, sQ, WhP, tmp, hbuf);
    segsum<<<2048, 256, 0, stream>>>(rowptr, hbuf, tmp);
    k_msg<<<1024, 256, 0, stream>>>(plist, qlist, sP, sQ, WhP, tmp, hbuf);
    segsum<<<2048, 256, 0, stream>>>(rowptr, hbuf, tmp);
    k_out<<<782, 256, 0, stream>>>(atomBf, WoP, tmp, out);
}

// Round 5
// 880.608 us; speedup vs baseline: 1.0274x; 1.0274x over previous
//
#include <hip/hip_runtime.h>

// DMPNN encoder, MI355X bf16-MFMA, round 5: alternating e-/f-layout so every
// kernel is in-place safe (reads and writes the SAME row) and at most one
// stream per kernel is random:
//   k_init : rows p (staged streaming), write e-layout @pidx[p] (scattered)
//   segsum1: sequential (e-layout)
//   k_msg1 : tmp0[sidx[p]] stream + h0@p stream -> h1 f-layout @p  (ALL STREAM)
//   segsum2: gather rows pidx[seg]  (full 256-B rows)
//   k_msg2 : tmp1[sidx[p]] stream + h1@pidx[p] random -> h2 e-layout @pidx[p]
//   segsum3: sequential (e-layout)
//   k_out  : stream
// Identities: fidx[p]=rev[eidx[p]], sidx[p]=dst[eidx[p]]=src[fidx[p]] sorted,
//   pidx[p]=posOf[fidx[p]] (fix-point-free involution),
//   src[eidx[p]]=dst[fidx[p]]=seg(pidx[p]).
//
// MFMA 16x16x32 bf16 layouts (learn_hip m89/m91):
//   A frag: lane l holds A[m=l&15][k=(l>>4)*8+j]
//   B frag: lane l holds B[k=(l>>4)*8+j][n=l&15] == W[n][k] k-contiguous
//   D frag: reg r holds D[row=(l>>4)*4+r][col=l&15]
// Weight output channels permuted (c(p) in cvt_w) so each lane's j=0/1 (2/3)
// fragments are adjacent channels -> epilogue stores packed u32 bf16x2.

typedef unsigned int u32;
typedef unsigned short u16;
using bf16x8 = __attribute__((ext_vector_type(8))) __bf16;
using f32x4  = __attribute__((ext_vector_type(4))) float;

#define NN 50000
#define NP 400000
#define NE 800000
#define AF 133
#define HID 128
#define ATU 68      // atomBf row stride in u32
#define KPU1 84     // k_init LDS stride; 80 data u32 = 160 cols = 5 chunks
#define KC1 5
#define KPU2 68     // k_msg stride; 64 data u32 = 128 cols = 4 chunks
#define KC2 4
#define KPU3 148    // k_out stride; 144 data u32 = 288 cols = 9 chunks
#define KC3 9
#define NCH 196     // scan chunks of 256 covering NN

__device__ __forceinline__ u16 f2bf(float f) {
    union { float f; u32 u; } x; x.f = f;
    u32 r = x.u + 0x7fffu + ((x.u >> 16) & 1u);   // RNE
    return (u16)(r >> 16);
}
__device__ __forceinline__ float bf2f(u16 b) {
    union { u32 u; float f; } x; x.u = ((u32)b) << 16;
    return x.f;
}
__device__ __forceinline__ float lo16(u32 v) { return bf2f((u16)v); }
__device__ __forceinline__ float hi16(u32 v) { return bf2f((u16)(v >> 16)); }
__device__ __forceinline__ u32 pack2(float a, float b) {
    return (u32)f2bf(a) | ((u32)f2bf(b) << 16);
}
__device__ __forceinline__ u32 sub2(u32 t, u32 h) {
    return pack2(lo16(t) - lo16(h), hi16(t) - hi16(h));
}
__device__ __forceinline__ float relu(float v) { return v > 0.f ? v : 0.f; }

// ---------------- precompute kernels ----------------

__global__ void cvt_atom(const float* __restrict__ atom, u32* __restrict__ out) {
    int total = NN * ATU;
    for (int i = blockIdx.x * blockDim.x + threadIdx.x; i < total; i += gridDim.x * blockDim.x) {
        int n = i / ATU;
        int cu = i - n * ATU;
        int k = 2 * cu;
        float f0 = (k < AF) ? atom[n * AF + k] : 0.f;
        float f1 = (k + 1 < AF) ? atom[n * AF + k + 1] : 0.f;
        out[i] = pack2(f0, f1);
    }
}

__device__ __forceinline__ float wcol(const float* W, int n, int Kw, int len1, int off2, int len2, int k) {
    if (k < len1) return W[n * Kw + k];
    int j = k - off2;
    if (j >= 0 && j < len2) return W[n * Kw + len1 + j];
    return 0.f;
}
// Wp row p <- actual channel c(p) (output-channel permutation for packed stores)
__global__ void cvt_w(const float* __restrict__ W, u32* __restrict__ out,
                      int Kw, int KpU, int len1, int off2, int len2) {
    int total = 128 * KpU;
    for (int i = blockIdx.x * blockDim.x + threadIdx.x; i < total; i += gridDim.x * blockDim.x) {
        int p = i / KpU;
        int cu = i - p * KpU;
        int t = p & 63;
        int c = (p & 64) + 2 * (t & 15) + ((t >> 4) & 1) + 32 * ((t >> 5) & 1);
        int k = 2 * cu;
        out[i] = pack2(wcol(W, c, Kw, len1, off2, len2, k),
                       wcol(W, c, Kw, len1, off2, len2, k + 1));
    }
}

// ---------------- CSR build ----------------

__global__ void hist(const int* __restrict__ dst, int* __restrict__ cnt) {
    for (int e = blockIdx.x * blockDim.x + threadIdx.x; e < NE; e += gridDim.x * blockDim.x)
        atomicAdd(&cnt[dst[e]], 1);
}

__global__ void scan1(const int* __restrict__ cnt, int* __restrict__ lexc, int* __restrict__ chunkSum) {
    __shared__ int s[256];
    int t = threadIdx.x, idx = blockIdx.x * 256 + t;
    int v = (idx < NN) ? cnt[idx] : 0;
    s[t] = v; __syncthreads();
    for (int off = 1; off < 256; off <<= 1) {
        int x = (t >= off) ? s[t - off] : 0;
        __syncthreads();
        s[t] += x;
        __syncthreads();
    }
    if (idx < NN) lexc[idx] = s[t] - v;
    if (t == 255) chunkSum[blockIdx.x] = s[255];
}

__global__ void scan2(const int* __restrict__ chunkSum, int* __restrict__ chunkOff) {
    __shared__ int s[256];
    int t = threadIdx.x;
    int v = (t < NCH) ? chunkSum[t] : 0;
    s[t] = v; __syncthreads();
    for (int off = 1; off < 256; off <<= 1) {
        int x = (t >= off) ? s[t - off] : 0;
        __syncthreads();
        s[t] += x;
        __syncthreads();
    }
    if (t < NCH) chunkOff[t] = s[t] - v;
}

__global__ void scan3(const int* __restrict__ lexc, const int* __restrict__ chunkOff,
                      int* __restrict__ rowptr, int* __restrict__ cursor) {
    int idx = blockIdx.x * 256 + threadIdx.x;
    if (idx < NN) {
        int v = lexc[idx] + chunkOff[blockIdx.x];
        rowptr[idx] = v;
        cursor[idx] = v;
    }
    if (idx == 0) rowptr[NN] = NE;
}

__global__ void scatter(const int* __restrict__ dst, const int* __restrict__ rev,
                        int* __restrict__ cursor, int* __restrict__ fidx,
                        int* __restrict__ sidx, int* __restrict__ posOf) {
    for (int e = blockIdx.x * blockDim.x + threadIdx.x; e < NE; e += gridDim.x * blockDim.x) {
        int d = dst[e];
        int pos = atomicAdd(&cursor[d], 1);
        fidx[pos] = rev[e];
        sidx[pos] = d;        // = src[fidx[pos]], nondecreasing over pos
        posOf[e] = pos;
    }
}

__global__ void pidx_build(const int* __restrict__ fidx, const int* __restrict__ posOf,
                           int* __restrict__ pidx) {
    for (int p = blockIdx.x * blockDim.x + threadIdx.x; p < NE; p += gridDim.x * blockDim.x)
        pidx[p] = posOf[fidx[p]];
}

// ---------------- segment sum ----------------
// one wave per node; chunk = 4 rows, lane l -> row (l>>4), uint4 col group (l&15).
// G=false: rows are sequential positions; G=true: rows gathered via gat[].
template<bool G>
__global__ __launch_bounds__(256)
void segsum_t(const int* __restrict__ rowptr, const int* __restrict__ gat,
              const u32* __restrict__ h, u32* __restrict__ tmp) {
    const int lane = threadIdx.x & 63;
    const int wv = threadIdx.x >> 6;
    const int rsel = lane >> 4;
    const int cg = lane & 15;
    const int nwaves = gridDim.x * 4;
    for (int n = blockIdx.x * 4 + wv; n < NN; n += nwaves) {
        int beg = rowptr[n], end = rowptr[n + 1];
        float a0 = 0, a1 = 0, a2 = 0, a3 = 0, a4 = 0, a5 = 0, a6 = 0, a7 = 0;
        int i = beg;
        for (; i + 8 <= end; i += 8) {
            int rA = G ? gat[i + rsel] : (i + rsel);
            int rB = G ? gat[i + 4 + rsel] : (i + 4 + rsel);
            uint4 hA = *(const uint4*)(h + (size_t)rA * 64 + 4 * cg);
            uint4 hB = *(const uint4*)(h + (size_t)rB * 64 + 4 * cg);
            a0 += lo16(hA.x) + lo16(hB.x); a1 += hi16(hA.x) + hi16(hB.x);
            a2 += lo16(hA.y) + lo16(hB.y); a3 += hi16(hA.y) + hi16(hB.y);
            a4 += lo16(hA.z) + lo16(hB.z); a5 += hi16(hA.z) + hi16(hB.z);
            a6 += lo16(hA.w) + lo16(hB.w); a7 += hi16(hA.w) + hi16(hB.w);
        }
        for (; i < end; i += 4) {
            if (i + rsel < end) {
                int rA = G ? gat[i + rsel] : (i + rsel);
                uint4 hA = *(const uint4*)(h + (size_t)rA * 64 + 4 * cg);
                a0 += lo16(hA.x); a1 += hi16(hA.x);
                a2 += lo16(hA.y); a3 += hi16(hA.y);
                a4 += lo16(hA.z); a5 += hi16(hA.z);
                a6 += lo16(hA.w); a7 += hi16(hA.w);
            }
        }
        a0 += __shfl_xor(a0, 16); a0 += __shfl_xor(a0, 32);
        a1 += __shfl_xor(a1, 16); a1 += __shfl_xor(a1, 32);
        a2 += __shfl_xor(a2, 16); a2 += __shfl_xor(a2, 32);
        a3 += __shfl_xor(a3, 16); a3 += __shfl_xor(a3, 32);
        a4 += __shfl_xor(a4, 16); a4 += __shfl_xor(a4, 32);
        a5 += __shfl_xor(a5, 16); a5 += __shfl_xor(a5, 32);
        a6 += __shfl_xor(a6, 16); a6 += __shfl_xor(a6, 32);
        a7 += __shfl_xor(a7, 16); a7 += __shfl_xor(a7, 32);
        if (rsel == 0) {
            uint4 o;
            o.x = pack2(a0, a1); o.y = pack2(a2, a3);
            o.z = pack2(a4, a5); o.w = pack2(a6, a7);
            *(uint4*)(tmp + (size_t)n * 64 + 4 * cg) = o;
        }
    }
}

// ---------------- k_init: pos-sequential 128-row tiles, 4 waves (64x64) ----------------
// writes e-layout: h0(fidx[p]) -> row pidx[p]
__global__ __launch_bounds__(256, 3)
void k_init(const u32* __restrict__ atomBf, const float* __restrict__ bond,
            const int* __restrict__ fidx, const int* __restrict__ sidx,
            const int* __restrict__ pidx, const u32* __restrict__ Wp,
            u32* __restrict__ hout)
{
    __shared__ u32 As[128 * KPU1];   // 43008 B -> 3 blocks/CU
    const int tid = threadIdx.x;
    const int lane = tid & 63;
    const int wv = tid >> 6;
    const int ln = lane & 15;
    const int q  = lane >> 4;
    const int rowBase = 64 * (wv >> 1);
    const int cbU = 32 * (wv & 1);
    const int ntiles = NE / 128;

    const int srow = tid >> 1;
    const int half = tid & 1;

    for (int tile = blockIdx.x; tile < ntiles; tile += gridDim.x) {
        const int e0 = tile * 128;
        {
            int p = e0 + srow;
            const u32* ap = atomBf + (size_t)sidx[p] * ATU;
            u32* dr = As + srow * KPU1;
            if (half == 0) {
                #pragma unroll
                for (int j = 0; j < 10; ++j)
                    *(uint4*)(dr + 4 * j) = *(const uint4*)(ap + 4 * j);
            } else {
                #pragma unroll
                for (int j = 10; j < 17; ++j)
                    *(uint4*)(dr + 4 * j) = *(const uint4*)(ap + 4 * j);
                const float* bp = bond + (size_t)fidx[p] * 14;
                float2 b0 = *(const float2*)(bp + 0);
                float2 b1 = *(const float2*)(bp + 2);
                float2 b2 = *(const float2*)(bp + 4);
                float2 b3 = *(const float2*)(bp + 6);
                float2 b4 = *(const float2*)(bp + 8);
                float2 b5 = *(const float2*)(bp + 10);
                float2 b6 = *(const float2*)(bp + 12);
                *(uint4*)(dr + 68) = make_uint4(pack2(b0.x, b0.y), pack2(b1.x, b1.y),
                                                pack2(b2.x, b2.y), pack2(b3.x, b3.y));
                *(uint4*)(dr + 72) = make_uint4(pack2(b4.x, b4.y), pack2(b5.x, b5.y),
                                                pack2(b6.x, b6.y), 0u);
                *(uint4*)(dr + 76) = make_uint4(0u, 0u, 0u, 0u);
            }
        }
        __syncthreads();

        f32x4 acc[4][4] = {};
        #pragma unroll
        for (int kc = 0; kc < KC1; ++kc) {
            const int kHalf = kc * 16 + q * 4;
            bf16x8 a[4], b[4];
            #pragma unroll
            for (int i = 0; i < 4; ++i)
                a[i] = *(const bf16x8*)(&As[(rowBase + 16 * i + ln) * KPU1 + kHalf]);
            #pragma unroll
            for (int j = 0; j < 4; ++j)
                b[j] = *(const bf16x8*)(Wp + (64 * (wv & 1) + 16 * j + ln) * KPU1 + kHalf);
            #pragma unroll
            for (int i = 0; i < 4; ++i)
                #pragma unroll
                for (int j = 0; j < 4; ++j)
                    acc[i][j] = __builtin_amdgcn_mfma_f32_16x16x32_bf16(a[i], b[j], acc[i][j], 0, 0, 0);
        }
        __syncthreads();

        #pragma unroll
        for (int i = 0; i < 4; ++i) {
            #pragma unroll
            for (int r = 0; r < 4; ++r) {
                int wpos = pidx[e0 + rowBase + 16 * i + q * 4 + r];
                u32* orow = hout + (size_t)wpos * 64;
                orow[cbU + ln]      = pack2(relu(acc[i][0][r]), relu(acc[i][1][r]));
                orow[cbU + 16 + ln] = pack2(relu(acc[i][2][r]), relu(acc[i][3][r]));
            }
        }
    }
}

// ---------------- k_msg: 128-row tiles, row p computes msg(fidx[p]) ----------------
// USEIDX=false: h row = p        (e-layout in, f-layout out)   all-stream
// USEIDX=true : h row = pidx[p]  (f-layout in, e-layout out)   random full rows
// Both read and write the SAME h row -> in-place safe.
template<bool USEIDX>
__global__ __launch_bounds__(256, 4)
void k_msg_t(const int* __restrict__ sidx, const int* __restrict__ pidx,
             const u32* __restrict__ Wp, const u32* __restrict__ tmp,
             u32* __restrict__ h)
{
    __shared__ u32 As[128 * KPU2];   // 34816 B -> 4 blocks/CU
    const int tid = threadIdx.x;
    const int lane = tid & 63;
    const int wv = tid >> 6;
    const int ln = lane & 15;
    const int q  = lane >> 4;
    const int rowBase = 64 * (wv >> 1);
    const int cbU = 32 * (wv & 1);
    const int ntiles = NE / 128;

    const int srow = tid >> 1;
    const int half = tid & 1;

    for (int tile = blockIdx.x; tile < ntiles; tile += gridDim.x) {
        const int e0 = tile * 128;
        {
            int p = e0 + srow;
            int hr = USEIDX ? pidx[p] : p;
            const u32* tp = tmp + (size_t)sidx[p] * 64 + half * 32;
            const u32* hp = h + (size_t)hr * 64 + half * 32;
            u32* dr = As + srow * KPU2 + half * 32;
            #pragma unroll
            for (int k = 0; k < 8; ++k) {
                uint4 tv = ((const uint4*)tp)[k];
                uint4 hv = ((const uint4*)hp)[k];
                uint4 o;
                o.x = sub2(tv.x, hv.x); o.y = sub2(tv.y, hv.y);
                o.z = sub2(tv.z, hv.z); o.w = sub2(tv.w, hv.w);
                ((uint4*)dr)[k] = o;
            }
        }
        __syncthreads();

        f32x4 acc[4][4] = {};
        #pragma unroll
        for (int kc = 0; kc < KC2; ++kc) {
            const int kHalf = kc * 16 + q * 4;
            bf16x8 a[4], b[4];
            #pragma unroll
            for (int i = 0; i < 4; ++i)
                a[i] = *(const bf16x8*)(&As[(rowBase + 16 * i + ln) * KPU2 + kHalf]);
            #pragma unroll
            for (int j = 0; j < 4; ++j)
                b[j] = *(const bf16x8*)(Wp + (64 * (wv & 1) + 16 * j + ln) * KPU2 + kHalf);
            #pragma unroll
            for (int i = 0; i < 4; ++i)
                #pragma unroll
                for (int j = 0; j < 4; ++j)
                    acc[i][j] = __builtin_amdgcn_mfma_f32_16x16x32_bf16(a[i], b[j], acc[i][j], 0, 0, 0);
        }
        __syncthreads();

        #pragma unroll
        for (int i = 0; i < 4; ++i) {
            #pragma unroll
            for (int r = 0; r < 4; ++r) {
                int p = e0 + rowBase + 16 * i + q * 4 + r;
                int wpos = USEIDX ? pidx[p] : p;
                u32* orow = h + (size_t)wpos * 64;
                orow[cbU + ln]      = pack2(relu(acc[i][0][r]), relu(acc[i][1][r]));
                orow[cbU + 16 + ln] = pack2(relu(acc[i][2][r]), relu(acc[i][3][r]));
            }
        }
    }
}

// ---------------- k_out: 64-node tiles, 4 waves (32x64 each) ----------------
__global__ __launch_bounds__(256, 4)
void k_out(const u32* __restrict__ atomBf, const u32* __restrict__ Wp,
           const u32* __restrict__ tmp, float* __restrict__ out)
{
    __shared__ u32 As[64 * KPU3];   // 37888 B -> 4 blocks/CU
    const int tid = threadIdx.x;
    const int lane = tid & 63;
    const int wv = tid >> 6;
    const int ln = lane & 15;
    const int q  = lane >> 4;
    const int rowBase = 32 * (wv >> 1);
    const int colBase = 64 * (wv & 1);
    const int ntiles = (NN + 63) / 64;

    const int srow = tid >> 2;
    const int qt = tid & 3;
    const uint4 z4 = make_uint4(0u, 0u, 0u, 0u);

    for (int tile = blockIdx.x; tile < ntiles; tile += gridDim.x) {
        const int n0 = tile * 64;
        {
            int n = n0 + srow;
            bool ok = n < NN;
            const u32* ap = atomBf + (size_t)n * ATU;
            const u32* tp = tmp + (size_t)n * 64;
            u32* dr = As + srow * KPU3;
            if (qt == 0) {
                #pragma unroll
                for (int j = 0; j < 9; ++j)
                    *(uint4*)(dr + 4 * j) = ok ? *(const uint4*)(ap + 4 * j) : z4;
            } else if (qt == 1) {
                #pragma unroll
                for (int j = 9; j < 17; ++j)
                    *(uint4*)(dr + 4 * j) = ok ? *(const uint4*)(ap + 4 * j) : z4;
            } else if (qt == 2) {
                #pragma unroll
                for (int j = 0; j < 8; ++j)
                    *(uint4*)(dr + 68 + 4 * j) = ok ? *(const uint4*)(tp + 4 * j) : z4;
                *(uint4*)(dr + 132) = z4;
            } else {
                #pragma unroll
                for (int j = 8; j < 16; ++j)
                    *(uint4*)(dr + 68 + 4 * j) = ok ? *(const uint4*)(tp + 4 * j) : z4;
                *(uint4*)(dr + 136) = z4;
                *(uint4*)(dr + 140) = z4;
            }
        }
        __syncthreads();

        f32x4 acc[2][4] = {};
        #pragma unroll
        for (int kc = 0; kc < KC3; ++kc) {
            const int kHalf = kc * 16 + q * 4;
            bf16x8 a[2], b[4];
            #pragma unroll
            for (int i = 0; i < 2; ++i)
                a[i] = *(const bf16x8*)(&As[(rowBase + 16 * i + ln) * KPU3 + kHalf]);
            #pragma unroll
            for (int j = 0; j < 4; ++j)
                b[j] = *(const bf16x8*)(Wp + (colBase + 16 * j + ln) * KPU3 + kHalf);
            #pragma unroll
            for (int i = 0; i < 2; ++i)
                #pragma unroll
                for (int j = 0; j < 4; ++j)
                    acc[i][j] = __builtin_amdgcn_mfma_f32_16x16x32_bf16(a[i], b[j], acc[i][j], 0, 0, 0);
        }
        __syncthreads();

        #pragma unroll
        for (int i = 0; i < 2; ++i) {
            #pragma unroll
            for (int r = 0; r < 4; ++r) {
                int n = n0 + rowBase + 16 * i + q * 4 + r;
                if (n < NN) {
                    float2* orow = (float2*)(out + (size_t)n * HID);
                    float2 v01, v23;
                    v01.x = relu(acc[i][0][r]); v01.y = relu(acc[i][1][r]);
                    v23.x = relu(acc[i][2][r]); v23.y = relu(acc[i][3][r]);
                    orow[(colBase >> 1) + ln]      = v01;
                    orow[(colBase >> 1) + 16 + ln] = v23;
                }
            }
        }
    }
}

// ---------------- launch ----------------

extern "C" void kernel_launch(void* const* d_in, const int* in_sizes, int n_in,
                              void* d_out, int out_size, void* d_ws, size_t ws_size,
                              hipStream_t stream) {
    const float* atom = (const float*)d_in[0];   // [50000][133]
    const float* bond = (const float*)d_in[1];   // [800000][14]
    const float* Wi   = (const float*)d_in[2];   // [128][147]
    const float* Wh   = (const float*)d_in[3];   // [128][128]
    const float* Wo   = (const float*)d_in[4];   // [128][261]
    const int*   src  = (const int*)d_in[5]; (void)src;
    const int*   dst  = (const int*)d_in[6];
    const int*   rev  = (const int*)d_in[7];
    float* out = (float*)d_out;

    char* ws = (char*)d_ws;
    size_t off = 0;
    auto take = [&](size_t bytes) { char* p = ws + off; off = (off + bytes + 255) & ~(size_t)255; return p; };
    u32* hbuf   = (u32*)take((size_t)NE * 64 * 4);     // 204.8 MB
    u32* tmp    = (u32*)take((size_t)NN * 64 * 4);     // 12.8 MB
    u32* atomBf = (u32*)take((size_t)NN * ATU * 4);    // 13.6 MB
    int* fidx   = (int*)take((size_t)NE * 4);
    int* sidx   = (int*)take((size_t)NE * 4);
    int* posOf  = (int*)take((size_t)NE * 4);
    int* pidx   = (int*)take((size_t)NE * 4);
    int* cnt    = (int*)take((size_t)NN * 4);
    int* lexc   = (int*)take((size_t)NN * 4);
    int* rowptr = (int*)take((size_t)(NN + 1) * 4);
    int* cursor = (int*)take((size_t)NN * 4);
    int* chunkSum = (int*)take(256 * 4);
    int* chunkOff = (int*)take(256 * 4);
    u32* WiP = (u32*)take(128 * KPU1 * 4);
    u32* WhP = (u32*)take(128 * KPU2 * 4);
    u32* WoP = (u32*)take(128 * KPU3 * 4);
    // total ~245 MB

    cvt_atom<<<2048, 256, 0, stream>>>(atom, atomBf);
    cvt_w<<<48, 256, 0, stream>>>(Wi, WiP, 147, KPU1, 133, 136, 14);
    cvt_w<<<48, 256, 0, stream>>>(Wh, WhP, 128, KPU2, 128, 1 << 20, 0);
    cvt_w<<<80, 256, 0, stream>>>(Wo, WoP, 261, KPU3, 133, 136, 128);

    hipMemsetAsync(cnt, 0, (size_t)NN * 4, stream);
    hist<<<1024, 256, 0, stream>>>(dst, cnt);
    scan1<<<NCH, 256, 0, stream>>>(cnt, lexc, chunkSum);
    scan2<<<1, 256, 0, stream>>>(chunkSum, chunkOff);
    scan3<<<NCH, 256, 0, stream>>>(lexc, chunkOff, rowptr, cursor);
    scatter<<<1024, 256, 0, stream>>>(dst, rev, cursor, fidx, sidx, posOf);
    pidx_build<<<1024, 256, 0, stream>>>(fidx, posOf, pidx);

    k_init<<<768, 256, 0, stream>>>(atomBf, bond, fidx, sidx, pidx, WiP, hbuf);   // e-layout
    segsum_t<false><<<2048, 256, 0, stream>>>(rowptr, nullptr, hbuf, tmp);        // sequential
    k_msg_t<false><<<2048, 256, 0, stream>>>(sidx, pidx, WhP, tmp, hbuf);         // all-stream -> f-layout
    segsum_t<true><<<2048, 256, 0, stream>>>(rowptr, pidx, hbuf, tmp);            // gather
    k_msg_t<true><<<2048, 256, 0, stream>>>(sidx, pidx, WhP, tmp, hbuf);          // random rows -> e-layout
    segsum_t<false><<<2048, 256, 0, stream>>>(rowptr, nullptr, hbuf, tmp);        // sequential
    k_out<<<782, 256, 0, stream>>>(atomBf, WoP, tmp, out);
}

// Round 6
// 819.408 us; speedup vs baseline: 1.1041x; 1.0747x over previous
//
#include <hip/hip_runtime.h>

// DMPNN encoder, MI355X bf16-MFMA, round 6: LDS-free barrier-free k_msg.
//
// Pipeline (pos-space, alternating e-/f-layout; identities:
//   fidx[p]=rev[eidx[p]], sidx[p]=dst[eidx[p]]=src[fidx[p]] (sorted),
//   pidx[p]=posOf[fidx[p]] fix-point-free involution):
//   k_init : staged LDS GEMM, write e-layout @pidx[p]
//   segsum1: sequential (e-layout)
//   k_msg1 : tmp0[sidx[p]] + h0@p -> h1 f-layout @p      (all-stream)
//   segsum2: gather rows pidx[seg]
//   k_msg2 : tmp1[sidx[p]] + h1@pidx[p] -> h2 e-layout @pidx[p]
//   segsum3: sequential
//   k_out  : stream
//
// k_msg is LDS/barrier-free: MFMA A-frag layout (lane l holds
// A[m=l&15][k=(l>>4)*8+j]) partitions the tile, so each lane builds its
// fragments straight from global (uint4 tmp - uint4 h -> bf16x8), one touch
// per byte. Wave tile 32x128: epilogue writes FULL 256-B h rows (4x64-B
// consecutive segment stores) -> no partial-line write amplification.
//
// Weight channel permutation c(p) = (p&64) + 2*(p&15) + ((p>>4)&1) + 32*((p>>5)&1)
// == 32*(p>>5) + 2*(p&15) + ((p>>4)&1) for p<128: lane ln's j-pair (2a,2a+1)
// holds adjacent channels 32a+2ln, 32a+2ln+1 -> packed u32 stores.

typedef unsigned int u32;
typedef unsigned short u16;
using bf16x8 = __attribute__((ext_vector_type(8))) __bf16;
using f32x4  = __attribute__((ext_vector_type(4))) float;

#define NN 50000
#define NP 400000
#define NE 800000
#define AF 133
#define HID 128
#define ATU 68      // atomBf row stride in u32
#define KPU1 84     // k_init LDS stride; 80 data u32 = 160 cols = 5 chunks
#define KC1 5
#define WHU 64      // Wh packed row stride (u32) = 256 B rows
#define KPU3 148    // k_out stride; 144 data u32 = 288 cols = 9 chunks
#define KC3 9
#define NCH 196     // scan chunks of 256 covering NN

__device__ __forceinline__ u16 f2bf(float f) {
    union { float f; u32 u; } x; x.f = f;
    u32 r = x.u + 0x7fffu + ((x.u >> 16) & 1u);   // RNE
    return (u16)(r >> 16);
}
__device__ __forceinline__ float bf2f(u16 b) {
    union { u32 u; float f; } x; x.u = ((u32)b) << 16;
    return x.f;
}
__device__ __forceinline__ float lo16(u32 v) { return bf2f((u16)v); }
__device__ __forceinline__ float hi16(u32 v) { return bf2f((u16)(v >> 16)); }
__device__ __forceinline__ u32 pack2(float a, float b) {
    return (u32)f2bf(a) | ((u32)f2bf(b) << 16);
}
__device__ __forceinline__ u32 sub2(u32 t, u32 h) {
    return pack2(lo16(t) - lo16(h), hi16(t) - hi16(h));
}
__device__ __forceinline__ float relu(float v) { return v > 0.f ? v : 0.f; }

union frag_cast { uint4 u; bf16x8 v; };

// ---------------- precompute kernels ----------------

__global__ void cvt_atom(const float* __restrict__ atom, u32* __restrict__ out) {
    int total = NN * ATU;
    for (int i = blockIdx.x * blockDim.x + threadIdx.x; i < total; i += gridDim.x * blockDim.x) {
        int n = i / ATU;
        int cu = i - n * ATU;
        int k = 2 * cu;
        float f0 = (k < AF) ? atom[n * AF + k] : 0.f;
        float f1 = (k + 1 < AF) ? atom[n * AF + k + 1] : 0.f;
        out[i] = pack2(f0, f1);
    }
}

__device__ __forceinline__ float wcol(const float* W, int n, int Kw, int len1, int off2, int len2, int k) {
    if (k < len1) return W[n * Kw + k];
    int j = k - off2;
    if (j >= 0 && j < len2) return W[n * Kw + len1 + j];
    return 0.f;
}
// Wp row p <- actual channel c(p) (output-channel permutation for packed stores)
__global__ void cvt_w(const float* __restrict__ W, u32* __restrict__ out,
                      int Kw, int KpU, int len1, int off2, int len2) {
    int total = 128 * KpU;
    for (int i = blockIdx.x * blockDim.x + threadIdx.x; i < total; i += gridDim.x * blockDim.x) {
        int p = i / KpU;
        int cu = i - p * KpU;
        int t = p & 63;
        int c = (p & 64) + 2 * (t & 15) + ((t >> 4) & 1) + 32 * ((t >> 5) & 1);
        int k = 2 * cu;
        out[i] = pack2(wcol(W, c, Kw, len1, off2, len2, k),
                       wcol(W, c, Kw, len1, off2, len2, k + 1));
    }
}

// ---------------- CSR build ----------------

__global__ void hist(const int* __restrict__ dst, int* __restrict__ cnt) {
    for (int e = blockIdx.x * blockDim.x + threadIdx.x; e < NE; e += gridDim.x * blockDim.x)
        atomicAdd(&cnt[dst[e]], 1);
}

__global__ void scan1(const int* __restrict__ cnt, int* __restrict__ lexc, int* __restrict__ chunkSum) {
    __shared__ int s[256];
    int t = threadIdx.x, idx = blockIdx.x * 256 + t;
    int v = (idx < NN) ? cnt[idx] : 0;
    s[t] = v; __syncthreads();
    for (int off = 1; off < 256; off <<= 1) {
        int x = (t >= off) ? s[t - off] : 0;
        __syncthreads();
        s[t] += x;
        __syncthreads();
    }
    if (idx < NN) lexc[idx] = s[t] - v;
    if (t == 255) chunkSum[blockIdx.x] = s[255];
}

__global__ void scan2(const int* __restrict__ chunkSum, int* __restrict__ chunkOff) {
    __shared__ int s[256];
    int t = threadIdx.x;
    int v = (t < NCH) ? chunkSum[t] : 0;
    s[t] = v; __syncthreads();
    for (int off = 1; off < 256; off <<= 1) {
        int x = (t >= off) ? s[t - off] : 0;
        __syncthreads();
        s[t] += x;
        __syncthreads();
    }
    if (t < NCH) chunkOff[t] = s[t] - v;
}

__global__ void scan3(const int* __restrict__ lexc, const int* __restrict__ chunkOff,
                      int* __restrict__ rowptr, int* __restrict__ cursor) {
    int idx = blockIdx.x * 256 + threadIdx.x;
    if (idx < NN) {
        int v = lexc[idx] + chunkOff[blockIdx.x];
        rowptr[idx] = v;
        cursor[idx] = v;
    }
    if (idx == 0) rowptr[NN] = NE;
}

__global__ void scatter(const int* __restrict__ dst, const int* __restrict__ rev,
                        int* __restrict__ cursor, int* __restrict__ fidx,
                        int* __restrict__ sidx, int* __restrict__ posOf) {
    for (int e = blockIdx.x * blockDim.x + threadIdx.x; e < NE; e += gridDim.x * blockDim.x) {
        int d = dst[e];
        int pos = atomicAdd(&cursor[d], 1);
        fidx[pos] = rev[e];
        sidx[pos] = d;        // = src[fidx[pos]], nondecreasing over pos
        posOf[e] = pos;
    }
}

__global__ void pidx_build(const int* __restrict__ fidx, const int* __restrict__ posOf,
                           int* __restrict__ pidx) {
    for (int p = blockIdx.x * blockDim.x + threadIdx.x; p < NE; p += gridDim.x * blockDim.x)
        pidx[p] = posOf[fidx[p]];
}

// ---------------- segment sum ----------------
// one wave per node; chunk = 4 rows, lane l -> row (l>>4), uint4 col group (l&15).
template<bool G>
__global__ __launch_bounds__(256)
void segsum_t(const int* __restrict__ rowptr, const int* __restrict__ gat,
              const u32* __restrict__ h, u32* __restrict__ tmp) {
    const int lane = threadIdx.x & 63;
    const int wv = threadIdx.x >> 6;
    const int rsel = lane >> 4;
    const int cg = lane & 15;
    const int nwaves = gridDim.x * 4;
    for (int n = blockIdx.x * 4 + wv; n < NN; n += nwaves) {
        int beg = rowptr[n], end = rowptr[n + 1];
        float a0 = 0, a1 = 0, a2 = 0, a3 = 0, a4 = 0, a5 = 0, a6 = 0, a7 = 0;
        int i = beg;
        for (; i + 8 <= end; i += 8) {
            int rA = G ? gat[i + rsel] : (i + rsel);
            int rB = G ? gat[i + 4 + rsel] : (i + 4 + rsel);
            uint4 hA = *(const uint4*)(h + (size_t)rA * 64 + 4 * cg);
            uint4 hB = *(const uint4*)(h + (size_t)rB * 64 + 4 * cg);
            a0 += lo16(hA.x) + lo16(hB.x); a1 += hi16(hA.x) + hi16(hB.x);
            a2 += lo16(hA.y) + lo16(hB.y); a3 += hi16(hA.y) + hi16(hB.y);
            a4 += lo16(hA.z) + lo16(hB.z); a5 += hi16(hA.z) + hi16(hB.z);
            a6 += lo16(hA.w) + lo16(hB.w); a7 += hi16(hA.w) + hi16(hB.w);
        }
        for (; i < end; i += 4) {
            if (i + rsel < end) {
                int rA = G ? gat[i + rsel] : (i + rsel);
                uint4 hA = *(const uint4*)(h + (size_t)rA * 64 + 4 * cg);
                a0 += lo16(hA.x); a1 += hi16(hA.x);
                a2 += lo16(hA.y); a3 += hi16(hA.y);
                a4 += lo16(hA.z); a5 += hi16(hA.z);
                a6 += lo16(hA.w); a7 += hi16(hA.w);
            }
        }
        a0 += __shfl_xor(a0, 16); a0 += __shfl_xor(a0, 32);
        a1 += __shfl_xor(a1, 16); a1 += __shfl_xor(a1, 32);
        a2 += __shfl_xor(a2, 16); a2 += __shfl_xor(a2, 32);
        a3 += __shfl_xor(a3, 16); a3 += __shfl_xor(a3, 32);
        a4 += __shfl_xor(a4, 16); a4 += __shfl_xor(a4, 32);
        a5 += __shfl_xor(a5, 16); a5 += __shfl_xor(a5, 32);
        a6 += __shfl_xor(a6, 16); a6 += __shfl_xor(a6, 32);
        a7 += __shfl_xor(a7, 16); a7 += __shfl_xor(a7, 32);
        if (rsel == 0) {
            uint4 o;
            o.x = pack2(a0, a1); o.y = pack2(a2, a3);
            o.z = pack2(a4, a5); o.w = pack2(a6, a7);
            *(uint4*)(tmp + (size_t)n * 64 + 4 * cg) = o;
        }
    }
}

// ---------------- k_init: pos-sequential 128-row tiles, LDS-staged ----------------
// writes e-layout: h0(fidx[p]) -> row pidx[p]
__global__ __launch_bounds__(256, 3)
void k_init(const u32* __restrict__ atomBf, const float* __restrict__ bond,
            const int* __restrict__ fidx, const int* __restrict__ sidx,
            const int* __restrict__ pidx, const u32* __restrict__ Wp,
            u32* __restrict__ hout)
{
    __shared__ u32 As[128 * KPU1];   // 43008 B -> 3 blocks/CU
    const int tid = threadIdx.x;
    const int lane = tid & 63;
    const int wv = tid >> 6;
    const int ln = lane & 15;
    const int q  = lane >> 4;
    const int rowBase = 64 * (wv >> 1);
    const int cbU = 32 * (wv & 1);
    const int ntiles = NE / 128;

    const int srow = tid >> 1;
    const int half = tid & 1;

    for (int tile = blockIdx.x; tile < ntiles; tile += gridDim.x) {
        const int e0 = tile * 128;
        {
            int p = e0 + srow;
            const u32* ap = atomBf + (size_t)sidx[p] * ATU;
            u32* dr = As + srow * KPU1;
            if (half == 0) {
                #pragma unroll
                for (int j = 0; j < 10; ++j)
                    *(uint4*)(dr + 4 * j) = *(const uint4*)(ap + 4 * j);
            } else {
                #pragma unroll
                for (int j = 10; j < 17; ++j)
                    *(uint4*)(dr + 4 * j) = *(const uint4*)(ap + 4 * j);
                const float* bp = bond + (size_t)fidx[p] * 14;
                float2 b0 = *(const float2*)(bp + 0);
                float2 b1 = *(const float2*)(bp + 2);
                float2 b2 = *(const float2*)(bp + 4);
                float2 b3 = *(const float2*)(bp + 6);
                float2 b4 = *(const float2*)(bp + 8);
                float2 b5 = *(const float2*)(bp + 10);
                float2 b6 = *(const float2*)(bp + 12);
                *(uint4*)(dr + 68) = make_uint4(pack2(b0.x, b0.y), pack2(b1.x, b1.y),
                                                pack2(b2.x, b2.y), pack2(b3.x, b3.y));
                *(uint4*)(dr + 72) = make_uint4(pack2(b4.x, b4.y), pack2(b5.x, b5.y),
                                                pack2(b6.x, b6.y), 0u);
                *(uint4*)(dr + 76) = make_uint4(0u, 0u, 0u, 0u);
            }
        }
        __syncthreads();

        f32x4 acc[4][4] = {};
        #pragma unroll
        for (int kc = 0; kc < KC1; ++kc) {
            const int kHalf = kc * 16 + q * 4;
            bf16x8 a[4], b[4];
            #pragma unroll
            for (int i = 0; i < 4; ++i)
                a[i] = *(const bf16x8*)(&As[(rowBase + 16 * i + ln) * KPU1 + kHalf]);
            #pragma unroll
            for (int j = 0; j < 4; ++j)
                b[j] = *(const bf16x8*)(Wp + (64 * (wv & 1) + 16 * j + ln) * KPU1 + kHalf);
            #pragma unroll
            for (int i = 0; i < 4; ++i)
                #pragma unroll
                for (int j = 0; j < 4; ++j)
                    acc[i][j] = __builtin_amdgcn_mfma_f32_16x16x32_bf16(a[i], b[j], acc[i][j], 0, 0, 0);
        }
        __syncthreads();

        #pragma unroll
        for (int i = 0; i < 4; ++i) {
            #pragma unroll
            for (int r = 0; r < 4; ++r) {
                int wpos = pidx[e0 + rowBase + 16 * i + q * 4 + r];
                u32* orow = hout + (size_t)wpos * 64;
                orow[cbU + ln]      = pack2(relu(acc[i][0][r]), relu(acc[i][1][r]));
                orow[cbU + 16 + ln] = pack2(relu(acc[i][2][r]), relu(acc[i][3][r]));
            }
        }
    }
}

// ---------------- k_msg: LDS-free, barrier-free; wave tile 32x128 ----------------
// block = 4 independent waves, each owns 32 rows: [tile*128 + 32*wv, +32).
// Row p: msg = tmp[sidx[p]] - h[hr],  hr = USEIDX ? pidx[p] : p.
// Result written back to row hr (same row read) -> in-place safe per-wave.
template<bool USEIDX>
__global__ __launch_bounds__(256)
void k_msg_t(const int* __restrict__ sidx, const int* __restrict__ pidx,
             const u32* __restrict__ Wp, const u32* __restrict__ tmp,
             u32* __restrict__ h)
{
    const int tid = threadIdx.x;
    const int lane = tid & 63;
    const int wv = tid >> 6;
    const int ln = lane & 15;
    const int q  = lane >> 4;
    const int e0 = blockIdx.x * 128 + 32 * wv;

    // build A fragments straight from global (one touch per byte)
    bf16x8 aF[2][4];
    #pragma unroll
    for (int i = 0; i < 2; ++i) {
        int p = e0 + 16 * i + ln;
        int srow = sidx[p];
        int hr = USEIDX ? pidx[p] : p;
        const u32* tb = tmp + (size_t)srow * 64 + q * 4;
        const u32* hb = h + (size_t)hr * 64 + q * 4;
        #pragma unroll
        for (int kc = 0; kc < 4; ++kc) {
            uint4 tv = *(const uint4*)(tb + kc * 16);
            uint4 hv = *(const uint4*)(hb + kc * 16);
            frag_cast fc;
            fc.u.x = sub2(tv.x, hv.x); fc.u.y = sub2(tv.y, hv.y);
            fc.u.z = sub2(tv.z, hv.z); fc.u.w = sub2(tv.w, hv.w);
            aF[i][kc] = fc.v;
        }
    }

    f32x4 acc[2][8] = {};
    #pragma unroll
    for (int kc = 0; kc < 4; ++kc) {
        bf16x8 b[8];
        #pragma unroll
        for (int j = 0; j < 8; ++j)
            b[j] = *(const bf16x8*)(Wp + (16 * j + ln) * WHU + kc * 16 + q * 4);
        #pragma unroll
        for (int i = 0; i < 2; ++i)
            #pragma unroll
            for (int j = 0; j < 8; ++j)
                acc[i][j] = __builtin_amdgcn_mfma_f32_16x16x32_bf16(aF[i][kc], b[j], acc[i][j], 0, 0, 0);
    }

    // epilogue: full 256-B rows, 4 consecutive 64-B segment stores per row
    #pragma unroll
    for (int i = 0; i < 2; ++i) {
        #pragma unroll
        for (int r = 0; r < 4; ++r) {
            int p = e0 + 16 * i + q * 4 + r;
            int wrow = USEIDX ? pidx[p] : p;
            u32* orow = h + (size_t)wrow * 64;
            #pragma unroll
            for (int a = 0; a < 4; ++a)
                orow[16 * a + ln] = pack2(relu(acc[i][2 * a][r]), relu(acc[i][2 * a + 1][r]));
        }
    }
}

// ---------------- k_out: 64-node tiles, 4 waves (32x64 each) ----------------
__global__ __launch_bounds__(256, 4)
void k_out(const u32* __restrict__ atomBf, const u32* __restrict__ Wp,
           const u32* __restrict__ tmp, float* __restrict__ out)
{
    __shared__ u32 As[64 * KPU3];   // 37888 B -> 4 blocks/CU
    const int tid = threadIdx.x;
    const int lane = tid & 63;
    const int wv = tid >> 6;
    const int ln = lane & 15;
    const int q  = lane >> 4;
    const int rowBase = 32 * (wv >> 1);
    const int colBase = 64 * (wv & 1);
    const int ntiles = (NN + 63) / 64;

    const int srow = tid >> 2;
    const int qt = tid & 3;
    const uint4 z4 = make_uint4(0u, 0u, 0u, 0u);

    for (int tile = blockIdx.x; tile < ntiles; tile += gridDim.x) {
        const int n0 = tile * 64;
        {
            int n = n0 + srow;
            bool ok = n < NN;
            const u32* ap = atomBf + (size_t)n * ATU;
            const u32* tp = tmp + (size_t)n * 64;
            u32* dr = As + srow * KPU3;
            if (qt == 0) {
                #pragma unroll
                for (int j = 0; j < 9; ++j)
                    *(uint4*)(dr + 4 * j) = ok ? *(const uint4*)(ap + 4 * j) : z4;
            } else if (qt == 1) {
                #pragma unroll
                for (int j = 9; j < 17; ++j)
                    *(uint4*)(dr + 4 * j) = ok ? *(const uint4*)(ap + 4 * j) : z4;
            } else if (qt == 2) {
                #pragma unroll
                for (int j = 0; j < 8; ++j)
                    *(uint4*)(dr + 68 + 4 * j) = ok ? *(const uint4*)(tp + 4 * j) : z4;
                *(uint4*)(dr + 132) = z4;
            } else {
                #pragma unroll
                for (int j = 8; j < 16; ++j)
                    *(uint4*)(dr + 68 + 4 * j) = ok ? *(const uint4*)(tp + 4 * j) : z4;
                *(uint4*)(dr + 136) = z4;
                *(uint4*)(dr + 140) = z4;
            }
        }
        __syncthreads();

        f32x4 acc[2][4] = {};
        #pragma unroll
        for (int kc = 0; kc < KC3; ++kc) {
            const int kHalf = kc * 16 + q * 4;
            bf16x8 a[2], b[4];
            #pragma unroll
            for (int i = 0; i < 2; ++i)
                a[i] = *(const bf16x8*)(&As[(rowBase + 16 * i + ln) * KPU3 + kHalf]);
            #pragma unroll
            for (int j = 0; j < 4; ++j)
                b[j] = *(const bf16x8*)(Wp + (colBase + 16 * j + ln) * KPU3 + kHalf);
            #pragma unroll
            for (int i = 0; i < 2; ++i)
                #pragma unroll
                for (int j = 0; j < 4; ++j)
                    acc[i][j] = __builtin_amdgcn_mfma_f32_16x16x32_bf16(a[i], b[j], acc[i][j], 0, 0, 0);
        }
        __syncthreads();

        #pragma unroll
        for (int i = 0; i < 2; ++i) {
            #pragma unroll
            for (int r = 0; r < 4; ++r) {
                int n = n0 + rowBase + 16 * i + q * 4 + r;
                if (n < NN) {
                    float2* orow = (float2*)(out + (size_t)n * HID);
                    float2 v01, v23;
                    v01.x = relu(acc[i][0][r]); v01.y = relu(acc[i][1][r]);
                    v23.x = relu(acc[i][2][r]); v23.y = relu(acc[i][3][r]);
                    orow[(colBase >> 1) + ln]      = v01;
                    orow[(colBase >> 1) + 16 + ln] = v23;
                }
            }
        }
    }
}

// ---------------- launch ----------------

extern "C" void kernel_launch(void* const* d_in, const int* in_sizes, int n_in,
                              void* d_out, int out_size, void* d_ws, size_t ws_size,
                              hipStream_t stream) {
    const float* atom = (const float*)d_in[0];   // [50000][133]
    const float* bond = (const float*)d_in[1];   // [800000][14]
    const float* Wi   = (const float*)d_in[2];   // [128][147]
    const float* Wh   = (const float*)d_in[3];   // [128][128]
    const float* Wo   = (const float*)d_in[4];   // [128][261]
    const int*   src  = (const int*)d_in[5]; (void)src;
    const int*   dst  = (const int*)d_in[6];
    const int*   rev  = (const int*)d_in[7];
    float* out = (float*)d_out;

    char* ws = (char*)d_ws;
    size_t off = 0;
    auto take = [&](size_t bytes) { char* p = ws + off; off = (off + bytes + 255) & ~(size_t)255; return p; };
    u32* hbuf   = (u32*)take((size_t)NE * 64 * 4);     // 204.8 MB
    u32* tmp    = (u32*)take((size_t)NN * 64 * 4);     // 12.8 MB
    u32* atomBf = (u32*)take((size_t)NN * ATU * 4);    // 13.6 MB
    int* fidx   = (int*)take((size_t)NE * 4);
    int* sidx   = (int*)take((size_t)NE * 4);
    int* posOf  = (int*)take((size_t)NE * 4);
    int* pidx   = (int*)take((size_t)NE * 4);
    int* cnt    = (int*)take((size_t)NN * 4);
    int* lexc   = (int*)take((size_t)NN * 4);
    int* rowptr = (int*)take((size_t)(NN + 1) * 4);
    int* cursor = (int*)take((size_t)NN * 4);
    int* chunkSum = (int*)take(256 * 4);
    int* chunkOff = (int*)take(256 * 4);
    u32* WiP = (u32*)take(128 * KPU1 * 4);
    u32* WhP = (u32*)take(128 * WHU * 4);
    u32* WoP = (u32*)take(128 * KPU3 * 4);
    // total ~245 MB

    cvt_atom<<<2048, 256, 0, stream>>>(atom, atomBf);
    cvt_w<<<48, 256, 0, stream>>>(Wi, WiP, 147, KPU1, 133, 136, 14);
    cvt_w<<<32, 256, 0, stream>>>(Wh, WhP, 128, WHU, 128, 1 << 20, 0);
    cvt_w<<<80, 256, 0, stream>>>(Wo, WoP, 261, KPU3, 133, 136, 128);

    hipMemsetAsync(cnt, 0, (size_t)NN * 4, stream);
    hist<<<1024, 256, 0, stream>>>(dst, cnt);
    scan1<<<NCH, 256, 0, stream>>>(cnt, lexc, chunkSum);
    scan2<<<1, 256, 0, stream>>>(chunkSum, chunkOff);
    scan3<<<NCH, 256, 0, stream>>>(lexc, chunkOff, rowptr, cursor);
    scatter<<<1024, 256, 0, stream>>>(dst, rev, cursor, fidx, sidx, posOf);
    pidx_build<<<1024, 256, 0, stream>>>(fidx, posOf, pidx);

    k_init<<<768, 256, 0, stream>>>(atomBf, bond, fidx, sidx, pidx, WiP, hbuf);   // e-layout
    segsum_t<false><<<2048, 256, 0, stream>>>(rowptr, nullptr, hbuf, tmp);        // sequential
    k_msg_t<false><<<NE / 128, 256, 0, stream>>>(sidx, pidx, WhP, tmp, hbuf);     // all-stream -> f-layout
    segsum_t<true><<<2048, 256, 0, stream>>>(rowptr, pidx, hbuf, tmp);            // gather
    k_msg_t<true><<<NE / 128, 256, 0, stream>>>(sidx, pidx, WhP, tmp, hbuf);      // random rows -> e-layout
    segsum_t<false><<<2048, 256, 0, stream>>>(rowptr, nullptr, hbuf, tmp);        // sequential
    k_out<<<782, 256, 0, stream>>>(atomBf, WoP, tmp, out);
}